// Round 1
// baseline (750.149 us; speedup 1.0000x reference)
//
#include <hip/hip_runtime.h>
#include <cmath>

// Problem constants (fixed by the reference file; active_size input == 512)
#define NB   32768
#define DIN  128
#define DMAX 1024
#define A    512

#define BM 64
#define BN 64
#define BK 32
#define LDA (BM + 4)   // pad keeps 16B alignment for b128 reads (pad % 4 == 0)
#define LDB (BN + 4)

__device__ __forceinline__ float sigm(float x) {
    return 1.0f / (1.0f + expf(-x));
}

__global__ __launch_bounds__(256) void gser_fused(
    const float* __restrict__ X,    // inputs      [NB, DIN]
    const float* __restrict__ P,    // prev_state  [NB, DMAX]
    const float* __restrict__ Wres, // [DMAX, DMAX] use [k<A, j<A], row stride DMAX
    const float* __restrict__ Win,  // [DMAX, DIN]  use rows < A
    const float* __restrict__ Wg,   // [3*DMAX, DIN] use rows < 3*A
    const float* __restrict__ lrp,  // [DMAX]
    const float* __restrict__ stp,  // [DMAX]
    float* __restrict__ out)        // [NB, DMAX]
{
    __shared__ float As [BK][LDA];
    __shared__ float Bs [BK][LDB];
    __shared__ float Bg0[BK][LDB];
    __shared__ float Bg1[BK][LDB];
    __shared__ float Bg2[BK][LDB];

    const int tid = threadIdx.x;
    const int tx = tid & 15;        // micro-tile col group
    const int ty = tid >> 4;        // micro-tile row group (0..15)
    const int j0 = blockIdx.x * BN; // column tile origin (0..448)
    const int b0 = blockIdx.y * BM; // row tile origin

    float acc[16], ai[16], af[16], ao[16];
#pragma unroll
    for (int i = 0; i < 16; ++i) { acc[i] = 0.f; ai[i] = 0.f; af[i] = 0.f; ao[i] = 0.f; }

    // staging indices
    const int lb  = tid >> 2;         // 0..63 : A-tile row (batch)
    const int lk8 = (tid & 3) * 8;    // 0,8,16,24 : A-tile k offset (8 floats)
    const int wk  = tid >> 4;         // 0..15 : W_res k row
    const int wj4 = (tid & 15) * 4;   // W_res j offset (4 floats)
    const int gj  = tid & 63;         // 0..63 : W_in/W_gate j (their row index)
    const int gk8 = (tid >> 6) * 8;   // 0,8,16,24 : their k offset

    for (int kt = 0; kt < 20; ++kt) {
        const int k0 = kt * BK;       // 0..608 over virtual K = A + DIN = 640
        if (k0 < A) {
            // ---- A tile from prev_state (cols k0..k0+31 < 512) ----
            const float* s = P + (b0 + lb) * DMAX + k0 + lk8;
            float4 v0 = *reinterpret_cast<const float4*>(s);
            float4 v1 = *reinterpret_cast<const float4*>(s + 4);
            As[lk8+0][lb] = v0.x; As[lk8+1][lb] = v0.y; As[lk8+2][lb] = v0.z; As[lk8+3][lb] = v0.w;
            As[lk8+4][lb] = v1.x; As[lk8+5][lb] = v1.y; As[lk8+6][lb] = v1.z; As[lk8+7][lb] = v1.w;
            // ---- B tile from W_res[k, j] (contiguous in j) ----
            float4 w0 = *reinterpret_cast<const float4*>(Wres + (k0 + wk) * DMAX + j0 + wj4);
            Bs[wk][wj4+0] = w0.x; Bs[wk][wj4+1] = w0.y; Bs[wk][wj4+2] = w0.z; Bs[wk][wj4+3] = w0.w;
            float4 w1 = *reinterpret_cast<const float4*>(Wres + (k0 + wk + 16) * DMAX + j0 + wj4);
            Bs[wk+16][wj4+0] = w1.x; Bs[wk+16][wj4+1] = w1.y; Bs[wk+16][wj4+2] = w1.z; Bs[wk+16][wj4+3] = w1.w;
        } else {
            const int koff = k0 - A;  // 0..96 into the DIN axis
            // ---- A tile from inputs ----
            const float* s = X + (b0 + lb) * DIN + koff + lk8;
            float4 v0 = *reinterpret_cast<const float4*>(s);
            float4 v1 = *reinterpret_cast<const float4*>(s + 4);
            As[lk8+0][lb] = v0.x; As[lk8+1][lb] = v0.y; As[lk8+2][lb] = v0.z; As[lk8+3][lb] = v0.w;
            As[lk8+4][lb] = v1.x; As[lk8+5][lb] = v1.y; As[lk8+6][lb] = v1.z; As[lk8+7][lb] = v1.w;
            // ---- B tiles from W_in / W_gate rows (stride DIN; transpose into LDS) ----
            {
                const float* wi = Win + (j0 + gj) * DIN + koff + gk8;
                float4 w0 = *reinterpret_cast<const float4*>(wi);
                float4 w1 = *reinterpret_cast<const float4*>(wi + 4);
                Bs[gk8+0][gj] = w0.x; Bs[gk8+1][gj] = w0.y; Bs[gk8+2][gj] = w0.z; Bs[gk8+3][gj] = w0.w;
                Bs[gk8+4][gj] = w1.x; Bs[gk8+5][gj] = w1.y; Bs[gk8+6][gj] = w1.z; Bs[gk8+7][gj] = w1.w;
            }
            {
                const float* wg = Wg + (0 * A + j0 + gj) * DIN + koff + gk8;
                float4 w0 = *reinterpret_cast<const float4*>(wg);
                float4 w1 = *reinterpret_cast<const float4*>(wg + 4);
                Bg0[gk8+0][gj] = w0.x; Bg0[gk8+1][gj] = w0.y; Bg0[gk8+2][gj] = w0.z; Bg0[gk8+3][gj] = w0.w;
                Bg0[gk8+4][gj] = w1.x; Bg0[gk8+5][gj] = w1.y; Bg0[gk8+6][gj] = w1.z; Bg0[gk8+7][gj] = w1.w;
            }
            {
                const float* wg = Wg + (1 * A + j0 + gj) * DIN + koff + gk8;
                float4 w0 = *reinterpret_cast<const float4*>(wg);
                float4 w1 = *reinterpret_cast<const float4*>(wg + 4);
                Bg1[gk8+0][gj] = w0.x; Bg1[gk8+1][gj] = w0.y; Bg1[gk8+2][gj] = w0.z; Bg1[gk8+3][gj] = w0.w;
                Bg1[gk8+4][gj] = w1.x; Bg1[gk8+5][gj] = w1.y; Bg1[gk8+6][gj] = w1.z; Bg1[gk8+7][gj] = w1.w;
            }
            {
                const float* wg = Wg + (2 * A + j0 + gj) * DIN + koff + gk8;
                float4 w0 = *reinterpret_cast<const float4*>(wg);
                float4 w1 = *reinterpret_cast<const float4*>(wg + 4);
                Bg2[gk8+0][gj] = w0.x; Bg2[gk8+1][gj] = w0.y; Bg2[gk8+2][gj] = w0.z; Bg2[gk8+3][gj] = w0.w;
                Bg2[gk8+4][gj] = w1.x; Bg2[gk8+5][gj] = w1.y; Bg2[gk8+6][gj] = w1.z; Bg2[gk8+7][gj] = w1.w;
            }
        }
        __syncthreads();

        if (k0 < A) {
#pragma unroll
            for (int kk = 0; kk < BK; ++kk) {
                float4 av4 = *reinterpret_cast<const float4*>(&As[kk][ty * 4]);
                float4 bv4 = *reinterpret_cast<const float4*>(&Bs[kk][tx * 4]);
                const float av[4] = {av4.x, av4.y, av4.z, av4.w};
                const float bv[4] = {bv4.x, bv4.y, bv4.z, bv4.w};
#pragma unroll
                for (int i = 0; i < 4; ++i)
#pragma unroll
                    for (int j = 0; j < 4; ++j)
                        acc[i * 4 + j] = fmaf(av[i], bv[j], acc[i * 4 + j]);
            }
        } else {
#pragma unroll
            for (int kk = 0; kk < BK; ++kk) {
                float4 av4 = *reinterpret_cast<const float4*>(&As[kk][ty * 4]);
                float4 bv4 = *reinterpret_cast<const float4*>(&Bs[kk][tx * 4]);
                float4 g0v = *reinterpret_cast<const float4*>(&Bg0[kk][tx * 4]);
                float4 g1v = *reinterpret_cast<const float4*>(&Bg1[kk][tx * 4]);
                float4 g2v = *reinterpret_cast<const float4*>(&Bg2[kk][tx * 4]);
                const float av[4] = {av4.x, av4.y, av4.z, av4.w};
                const float bv[4] = {bv4.x, bv4.y, bv4.z, bv4.w};
                const float g0[4] = {g0v.x, g0v.y, g0v.z, g0v.w};
                const float g1[4] = {g1v.x, g1v.y, g1v.z, g1v.w};
                const float g2[4] = {g2v.x, g2v.y, g2v.z, g2v.w};
#pragma unroll
                for (int i = 0; i < 4; ++i) {
#pragma unroll
                    for (int j = 0; j < 4; ++j) {
                        acc[i * 4 + j] = fmaf(av[i], bv[j], acc[i * 4 + j]);
                        ai [i * 4 + j] = fmaf(av[i], g0[j], ai [i * 4 + j]);
                        af [i * 4 + j] = fmaf(av[i], g1[j], af [i * 4 + j]);
                        ao [i * 4 + j] = fmaf(av[i], g2[j], ao [i * 4 + j]);
                    }
                }
            }
        }
        __syncthreads();
    }

    // ---- epilogue: gating + leak + tanh + spike threshold, plus zero-pad ----
    float leakv[4], thrv[4];
#pragma unroll
    for (int jj = 0; jj < 4; ++jj) {
        const int c = j0 + tx * 4 + jj;
        leakv[jj] = sigm(lrp[c]);              // sigmoid(leak_rate_param)
        thrv[jj]  = log1pf(expf(stp[c]));      // softplus(spike_threshold_param)
    }
#pragma unroll
    for (int ii = 0; ii < 4; ++ii) {
        const int r = b0 + ty * 4 + ii;
        float4 pv4 = *reinterpret_cast<const float4*>(P + r * DMAX + j0 + tx * 4);
        const float pv[4] = {pv4.x, pv4.y, pv4.z, pv4.w};
        float4 res;
        float* rp = &res.x;
#pragma unroll
        for (int jj = 0; jj < 4; ++jj) {
            const int idx = ii * 4 + jj;
            const float s1 = acc[idx];         // input_part + reservoir_part
            const float ig = sigm(ai[idx]);
            const float fg = sigm(af[idx]);
            const float og = sigm(ao[idx]);
            float st = (1.0f - leakv[jj]) * (fg * pv[jj]) + leakv[jj] * tanhf(ig * s1);
            st *= og;
            st = (st > thrv[jj]) ? (st - thrv[jj]) : st;
            rp[jj] = st;
        }
        *reinterpret_cast<float4*>(out + r * DMAX + j0 + tx * 4) = res;
        float4 z; z.x = 0.f; z.y = 0.f; z.z = 0.f; z.w = 0.f;
        *reinterpret_cast<float4*>(out + r * DMAX + A + j0 + tx * 4) = z;  // pad cols [512,1024)
    }
}

extern "C" void kernel_launch(void* const* d_in, const int* in_sizes, int n_in,
                              void* d_out, int out_size, void* d_ws, size_t ws_size,
                              hipStream_t stream) {
    const float* X    = (const float*)d_in[0]; // inputs
    const float* P    = (const float*)d_in[1]; // prev_state
    const float* Wres = (const float*)d_in[2];
    const float* Win  = (const float*)d_in[3];
    const float* Wg   = (const float*)d_in[4];
    const float* lrp  = (const float*)d_in[5];
    const float* stp  = (const float*)d_in[6];
    // d_in[7] = active_size (== 512, fixed by problem config; hard-coded as A)
    float* out = (float*)d_out;

    dim3 grid(A / BN, NB / BM, 1);   // (8, 512)
    dim3 block(256, 1, 1);
    hipLaunchKernelGGL(gser_fused, grid, block, 0, stream, X, P, Wres, Win, Wg, lrp, stp, out);
}